// Round 9
// baseline (209.453 us; speedup 1.0000x reference)
//
#include <hip/hip_runtime.h>
#include <hip/hip_bf16.h>

typedef __attribute__((ext_vector_type(8))) short bf16x8;
typedef __attribute__((ext_vector_type(4))) float f32x4;
typedef __attribute__((ext_vector_type(16))) float f32x16;

#define DI __device__ __forceinline__

static constexpr int Bb  = 2;
static constexpr int Tt  = 1024;
static constexpr int Cc  = 2048;
static constexpr int Hh  = 16;
static constexpr int Dd  = 128;
static constexpr int TC  = 1024;   // cached tokens (seq_start)
static constexpr int CTX = 2048;   // total context
static constexpr int LDP = 2112;   // padded row stride for GEMM operands
static constexpr int VS  = 2080;   // padded Vt row stride
static constexpr float QSCALE = 0.08838834764831845f; // 1/sqrt(128)

DI unsigned short f2bf(float f){
  unsigned u = __builtin_bit_cast(unsigned, f);
  u += 0x7FFFu + ((u >> 16) & 1u);
  return (unsigned short)(u >> 16);
}
DI float bf2f(unsigned short s){
  return __builtin_bit_cast(float, (unsigned)s << 16);
}
DI unsigned pk2(float a, float b){
  return (unsigned)f2bf(a) | ((unsigned)f2bf(b) << 16);
}
DI bf16x8 mk4(unsigned a, unsigned b, unsigned c, unsigned d){
  union{ unsigned u[4]; bf16x8 v; } x;
  x.u[0]=a; x.u[1]=b; x.u[2]=c; x.u[3]=d; return x.v;
}
DI f32x16 mfma32(bf16x8 a, bf16x8 b, f32x16 c){
  return __builtin_amdgcn_mfma_f32_32x32x16_bf16(a, b, c, 0, 0, 0);
}
#define MFMA16(a,b,c) __builtin_amdgcn_mfma_f32_16x16x32_bf16(a,b,c,0,0,0)
DI void gld16(const void* g, void* l){
  __builtin_amdgcn_global_load_lds(
      (const __attribute__((address_space(1))) unsigned int*)g,
      (__attribute__((address_space(3))) unsigned int*)l, 16, 0, 0);
}
DI unsigned ldsoff(const void* p){
  return (unsigned)(size_t)(const __attribute__((address_space(3))) void*)p;
}
// inline-asm LDS read: compiler-invisible (manual lgkmcnt + sched_barrier required)
template<int OFF>
DI bf16x8 dsr(unsigned addr){
  bf16x8 v;
  if constexpr (OFF == 0)
    asm volatile("ds_read_b128 %0, %1" : "=v"(v) : "v"(addr));
  else
    asm volatile("ds_read_b128 %0, %1 offset:%2" : "=v"(v) : "v"(addr), "i"(OFF));
  return v;
}
// NO-CLOBBER fences: invisible to the waitcnt pass (no mayLoad/mayStore),
// so no implicit vmcnt(0) drain of in-flight LDS-DMA is inserted around them.
#define BARNC   asm volatile("s_barrier")
#define LGKM0   asm volatile("s_waitcnt lgkmcnt(0)")
#define VMCNT4  asm volatile("s_waitcnt vmcnt(4)")
#define VMCNT0  asm volatile("s_waitcnt vmcnt(0)")
#define SBAR    __builtin_amdgcn_sched_barrier(0)

// ---- shared transpose body: fp32 [R][C] -> bf16 [C][ostride] swizzled ----
DI void transpose_body(const float* in, unsigned short* out,
                       int R, int C, int ostride, int r0, int c0, int mode,
                       unsigned short (*tile)[33]){
  int tx = threadIdx.x & 31, ty = threadIdx.x >> 5;
#pragma unroll
  for(int i=0;i<4;i++){
    int r = r0 + ty + i*8;
    tile[ty + i*8][tx] = f2bf(in[(size_t)r * C + c0 + tx]);
  }
  __syncthreads();
#pragma unroll
  for(int i=0;i<4;i++){
    int c = c0 + ty + i*8;     // out row
    int k = r0 + tx;           // out col (logical)
    int kp;
    if(mode == 0)
      kp = (k & ~24) | ((((k>>3)&3) ^ ((c>>1)&3)) << 3);
    else
      kp = (k & ~56) | ((((k>>3)&7) ^ (c&7)) << 3);
    out[(size_t)c * ostride + kp] = tile[tx][ty + i*8];
  }
}

// ---- fused pre-work: W_qkv transpose (MODE 0) + x conv (MODE 0) + cache copy ----
__global__ __launch_bounds__(256) void fused_pre_k(
    const float* __restrict__ W_qkv, unsigned short* __restrict__ WqkvT,
    const float4* __restrict__ x4, unsigned short* __restrict__ xbf,
    const float4* __restrict__ ck, const float4* __restrict__ cv,
    float4* __restrict__ ok, float4* __restrict__ ov,
    unsigned short* __restrict__ Kws){
  __shared__ unsigned short tile[32][33];
  int bid = blockIdx.x;
  if(bid < 12288){
    int bx = bid % 192, by = bid / 192;
    transpose_body(W_qkv, WqkvT, 2048, 6144, LDP, by*32, bx*32, 0, tile);
  } else if(bid < 16384){
    int idx = (bid - 12288) * 256 + threadIdx.x;   // x: 2048*2048/4
    int m = idx >> 9;
    int c4 = (idx & 511) * 4;
    float4 v = x4[idx];
    int cp = (c4 & ~24) | ((((c4>>3)&3) ^ ((m>>1)&3)) << 3);
    uint2 p; p.x = pk2(v.x, v.y); p.y = pk2(v.z, v.w);
    *(uint2*)(xbf + (size_t)m * LDP + cp) = p;
  } else {
    int idx = (bid - 16384) * 256 + threadIdx.x;
    const int per = TC * Dd / 4;                 // 32768 per (b,h)
    int bh = idx / per, r = idx - bh * per;
    int dst = bh * (CTX * Dd / 4) + r;
    float4 kv = ck[idx];
    ok[dst] = kv;
    ov[dst] = cv[idx];
    int key = r >> 5, dq = (r & 31) * 4;
    int dp = (((dq>>3) ^ (key&7)) << 3) | (dq & 7);
    uint2 p; p.x = pk2(kv.x, kv.y); p.y = pk2(kv.z, kv.w);
    *(uint2*)(Kws + ((size_t)bh * CTX + key) * Dd + dp) = p;
  }
}

// ---- fused mid-work: V^T (per bh, MODE 1) + W_proj^T (MODE 0) ----
__global__ __launch_bounds__(256) void fused_mid_k(
    const float* __restrict__ out_v, unsigned short* __restrict__ Vt_ws,
    const float* __restrict__ W_proj, unsigned short* __restrict__ WprojT){
  __shared__ unsigned short tile[32][33];
  int bid = blockIdx.x;
  if(bid < 8192){
    int z = bid >> 8, rem = bid & 255;
    int bx = rem & 3, by = rem >> 2;
    transpose_body(out_v + (size_t)z*2048*128, Vt_ws + (size_t)z*128*VS,
                   2048, 128, VS, by*32, bx*32, 1, tile);
  } else {
    int b2 = bid - 8192;
    int bx = b2 & 63, by = b2 >> 6;
    transpose_body(W_proj, WprojT, 2048, 2048, LDP, by*32, bx*32, 0, tile);
  }
}

// ===== unified 128x128 BK=32 GEMM, counted-vmcnt, 4 blocks/CU =====
// A, BT bf16 MODE-0 swizzled, stride LDP. NT = n-tiles (grid = 16*NT, 1D).
// EPI 0: QKV scatter. EPI 1: bias + fp32 store.
template<int EPI, int NT>
__global__ __launch_bounds__(256, 4) void gemm_t(
    const unsigned short* __restrict__ A, const unsigned short* __restrict__ BT,
    unsigned short* __restrict__ q_ws, float* __restrict__ out_k,
    float* __restrict__ out_v, unsigned short* __restrict__ Kws,
    const float* __restrict__ bias, float* __restrict__ outp){
  constexpr int K = 2048;
  __shared__ unsigned short Al[2][128*32];   // 16 KiB
  __shared__ unsigned short Bl[2][128*32];   // 16 KiB
  int tid = threadIdx.x, lane = tid & 63, w = tid >> 6;
  int lr = lane & 15, lg = lane >> 4;
  constexpr int NWG = 16 * NT;
  int bid = blockIdx.x;                      // NWG % 8 == 0
  int swz = (bid & 7) * (NWG/8) + (bid >> 3);
  int m0 = (swz & 15) * 128;
  int n0 = (swz >> 4) * 128;
  int wr = (w >> 1) * 64, wc = (w & 1) * 64;
  int fsw = (lg ^ ((lr >> 1) & 3)) << 3;

  unsigned baseAb = ldsoff(Al) + (unsigned)(((wr + lr)*32 + fsw)*2);
  unsigned baseBb = ldsoff(Bl) + (unsigned)(((wc + lr)*32 + fsw)*2);

  f32x4 acc[4][4];
#pragma unroll
  for(int i=0;i<4;i++)
#pragma unroll
    for(int j=0;j<4;j++) acc[i][j] = (f32x4){0.f,0.f,0.f,0.f};

  auto stage = [&](int buf, int k0){
#pragma unroll
    for(int li=0; li<2; li++){
      int rb = w*32 + li*16;
      gld16(A  + (size_t)(m0 + rb + (lane>>2))*LDP + k0 + (lane&3)*8, &Al[buf][rb*32]);
      gld16(BT + (size_t)(n0 + rb + (lane>>2))*LDP + k0 + (lane&3)*8, &Bl[buf][rb*32]);
    }
  };
  stage(0, 0);                      // 4 loads in flight
  int buf = 0;
#pragma unroll 1
  for(int k0 = 0; k0 < K; k0 += 32){
    SBAR;
    if(k0 + 32 < K){
      stage(buf^1, k0 + 32);        // +4 -> 8 in flight
      SBAR;
      VMCNT4;                       // buf's 4 landed; next-buf 4 stay in flight
    } else {
      SBAR;
      VMCNT0;
    }
    BARNC;                          // all waves' buf loads landed
    unsigned aA = baseAb + (unsigned)buf*8192u;
    unsigned aB = baseBb + (unsigned)buf*8192u;
    bf16x8 af[4], bfr[4];
    af[0]  = dsr<0>(aA);    af[1]  = dsr<1024>(aA);
    af[2]  = dsr<2048>(aA); af[3]  = dsr<3072>(aA);
    bfr[0] = dsr<0>(aB);    bfr[1] = dsr<1024>(aB);
    bfr[2] = dsr<2048>(aB); bfr[3] = dsr<3072>(aB);
    LGKM0;
    SBAR;
    __builtin_amdgcn_s_setprio(1);
#pragma unroll
    for(int mi=0;mi<4;mi++)
#pragma unroll
      for(int ni=0;ni<4;ni++)
        acc[mi][ni] = MFMA16(af[mi], bfr[ni], acc[mi][ni]);
    __builtin_amdgcn_s_setprio(0);
    SBAR;
    BARNC;                          // reads done before next iter overwrites buf
    buf ^= 1;
  }

#pragma unroll
  for(int mi=0;mi<4;mi++){
#pragma unroll
    for(int ni=0;ni<4;ni++){
      int n = n0 + wc + ni*16 + lr;
#pragma unroll
      for(int r=0;r<4;r++){
        int mrow = m0 + wr + mi*16 + lg*4 + r;
        float v = acc[mi][ni][r];
        if constexpr (EPI == 0){
          int seg = n >> 11;
          int h = (n >> 7) & 15, d = n & 127;
          int b = mrow >> 10, t = mrow & 1023;
          if(seg == 0){
            q_ws[((size_t)(b*Hh + h)*Tt + t)*Dd + d] = f2bf(v * QSCALE);
          } else if(seg == 1){
            int key = TC + t;
            size_t base = (size_t)(b*Hh + h)*CTX + key;
            out_k[base*Dd + d] = v;
            int dp = (((d>>3) ^ (key&7)) << 3) | (d & 7);
            Kws[base*Dd + dp] = f2bf(v);
          } else {
            out_v[((size_t)(b*Hh + h)*CTX + TC + t)*Dd + d] = v;
          }
        } else {
          outp[(size_t)mrow * Cc + n] = v + bias[n];
        }
      }
    }
  }
}

// ---- flash attention, swapped-QK 32x32, 4 waves x 32q, key-split x2 ----
__global__ __launch_bounds__(256, 2) void attn_k(
    const unsigned short* __restrict__ q_ws,
    const unsigned short* __restrict__ Kws,
    const unsigned short* __restrict__ Vt,
    float* __restrict__ O0, unsigned short* __restrict__ O1b,
    float* __restrict__ ml){
  __shared__ unsigned short Kl[2][64*128];   // [key][128] swizzled
  __shared__ unsigned short Vl[2][128*64];   // [d][64]  swizzled
  int tid = threadIdx.x, lane = tid & 63, w = tid >> 6;
  int l31 = lane & 31, hi = lane >> 5, r7 = l31 & 7;
  int qt = blockIdx.x, split = blockIdx.y, bh = blockIdx.z;
  int q0b = qt * 128, qw0 = q0b + w * 32;
  const unsigned short* Kb = Kws + (size_t)bh * CTX * Dd;
  const unsigned short* Vb = Vt  + (size_t)bh * Dd * VS;

  const unsigned short* qp = q_ws + ((size_t)bh * Tt + qw0 + l31) * Dd + hi * 8;
  bf16x8 qf[8];
#pragma unroll
  for(int ks=0;ks<8;ks++) qf[ks] = *(const bf16x8*)(qp + ks*16);

  f32x16 o[4];
#pragma unroll
  for(int dt=0;dt<4;dt++)
#pragma unroll
    for(int r=0;r<16;r++) o[dt][r] = 0.f;
  float m = -3e38f, l = 0.f;

  int nts = ((TC + q0b + 128) >> 6) >> 1;   // tiles for this split

  auto stageK = [&](int buf, int j0){
#pragma unroll
    for(int li=0; li<4; li++){
      gld16(Kb + (size_t)(j0 + w*16 + li*4 + (lane>>4))*Dd + (lane&15)*8,
            &Kl[buf][(w*16 + li*4)*128]);
    }
  };
  auto stageV = [&](int buf, int j0){
#pragma unroll
    for(int li=0; li<4; li++){
      gld16(Vb + (size_t)(w*32 + li*8 + (lane>>3))*VS + j0 + (lane&7)*8,
            &Vl[buf][(w*32 + li*8)*64]);
    }
  };

  stageK(0, split*64); stageV(0, split*64);
  __syncthreads();
  int buf = 0;
#pragma unroll 1
  for(int t = 0; t < nts; t++){
    int j0 = (2*t + split) * 64;
    if(t + 1 < nts){ stageK(buf^1, j0 + 128); stageV(buf^1, j0 + 128); }

    if(j0 <= TC + qw0 + 31){
      f32x16 s0, s1;
#pragma unroll
      for(int r=0;r<16;r++){ s0[r] = 0.f; s1[r] = 0.f; }
#pragma unroll
      for(int ks=0; ks<8; ks++){
        int ub = ((ks*2 + hi) ^ r7) << 3;
        bf16x8 kf0 = *(const bf16x8*)&Kl[buf][l31*128 + ub];
        bf16x8 kf1 = *(const bf16x8*)&Kl[buf][(32+l31)*128 + ub];
        s0 = mfma32(kf0, qf[ks], s0);
        s1 = mfma32(kf1, qf[ks], s1);
      }
      int qabs = TC + qw0 + l31;
      if(j0 + 63 > TC + qw0){
#pragma unroll
        for(int r=0;r<16;r++){
          int kk = (r&3) + 8*(r>>2) + 4*hi;
          if(j0 + kk > qabs)      s0[r] = -1e30f;
          if(j0 + 32 + kk > qabs) s1[r] = -1e30f;
        }
      }
      float tm = fmaxf(s0[0], s1[0]);
#pragma unroll
      for(int r=1;r<16;r++) tm = fmaxf(tm, fmaxf(s0[r], s1[r]));
      tm = fmaxf(tm, __shfl_xor(tm, 32, 64));
      if(!__all(tm - m <= 8.f)){
        float mn = fmaxf(m, tm);
        float alpha = __expf(m - mn);
        m = mn;
        l *= alpha;
        float ar[16];
#pragma unroll
        for(int r=0;r<16;r++){
          int kk = (r&3) + 8*(r>>2) + 4*hi;
          ar[r] = __shfl(alpha, kk, 64);
        }
#pragma unroll
        for(int dt=0;dt<4;dt++)
#pragma unroll
          for(int r=0;r<16;r++) o[dt][r] *= ar[r];
      }
#pragma unroll
      for(int r=0;r<16;r++){ s0[r] = __expf(s0[r] - m); s1[r] = __expf(s1[r] - m); }
      float ts = 0.f;
#pragma unroll
      for(int r=0;r<16;r++) ts += s0[r] + s1[r];
      ts += __shfl_xor(ts, 32, 64);
      l += ts;
#pragma unroll
      for(int ks16=0; ks16<4; ks16++){
        f32x16 p = (ks16 & 2) ? s1 : s0;
        int fb = (ks16 & 1) * 8;
        unsigned e0 = pk2(p[fb+0], p[fb+1]);
        unsigned e1 = pk2(p[fb+2], p[fb+3]);
        unsigned e2 = pk2(p[fb+4], p[fb+5]);
        unsigned e3 = pk2(p[fb+6], p[fb+7]);
        unsigned x0 = __shfl_xor(e0, 32, 64);
        unsigned x1 = __shfl_xor(e1, 32, 64);
        unsigned x2 = __shfl_xor(e2, 32, 64);
        unsigned x3 = __shfl_xor(e3, 32, 64);
        bf16x8 pa = mk4(hi ? x2 : e0, hi ? x3 : e1, hi ? e2 : x0, hi ? e3 : x1);
        int ub = ((ks16*2 + hi) ^ r7) << 3;
#pragma unroll
        for(int dt=0; dt<4; dt++){
          bf16x8 vf = *(const bf16x8*)&Vl[buf][(dt*32 + l31)*64 + ub];
          o[dt] = mfma32(pa, vf, o[dt]);
        }
      }
    }
    __syncthreads();
    buf ^= 1;
  }

  if(split == 0){
#pragma unroll
    for(int dt=0; dt<4; dt++)
#pragma unroll
      for(int r=0; r<16; r++){
        int q = qw0 + (r&3) + 8*(r>>2) + 4*hi;
        O0[((size_t)bh*Tt + q)*Dd + dt*32 + l31] = o[dt][r];
      }
  } else {
#pragma unroll
    for(int dt=0; dt<4; dt++)
#pragma unroll
      for(int r=0; r<16; r++){
        int q = qw0 + (r&3) + 8*(r>>2) + 4*hi;
        O1b[((size_t)bh*Tt + q)*Dd + dt*32 + l31] = f2bf(o[dt][r]);
      }
  }
  if(lane < 32){
    float* mlp = ml + (((size_t)split*32 + bh)*Tt + qw0 + l31)*2;
    mlp[0] = m; mlp[1] = l;
  }
}

// ---- combine split partials -> bf16 attn_ws (MODE-0 swizzle, stride LDP) ----
__global__ __launch_bounds__(256) void combine_k(
    const float* __restrict__ O0, const unsigned short* __restrict__ O1b,
    const float* __restrict__ ml, unsigned short* __restrict__ attn_ws){
  int tid = threadIdx.x;
  int d = tid & 127, rl = tid >> 7;
  int row = blockIdx.x * 2 + rl;          // bh*1024 + t
  int bh = row >> 10, t = row & 1023;
  const float* p0 = ml + ((size_t)bh * Tt + t) * 2;
  const float* p1 = ml + (((size_t)32 + bh) * Tt + t) * 2;
  float m0 = p0[0], l0 = p0[1], m1 = p1[0], l1 = p1[1];
  float M = fmaxf(m0, m1);
  float e0 = __expf(m0 - M), e1 = __expf(m1 - M);
  float inv = 1.f / (l0*e0 + l1*e1);
  size_t off = (size_t)row * Dd + d;
  float v = (O0[off]*e0 + bf2f(O1b[off])*e1) * inv;
  int b = bh >> 4, h = bh & 15;
  int mrow = b * Tt + t;
  int c = h * Dd + d;
  int cp = (c & ~24) | ((((c>>3)&3) ^ ((mrow>>1)&3)) << 3);
  attn_ws[(size_t)mrow * LDP + cp] = f2bf(v);
}

extern "C" void kernel_launch(void* const* d_in, const int* in_sizes, int n_in,
                              void* d_out, int out_size, void* d_ws, size_t ws_size,
                              hipStream_t stream){
  const float* x       = (const float*)d_in[0];
  const float* cache_k = (const float*)d_in[1];
  const float* cache_v = (const float*)d_in[2];
  const float* W_qkv   = (const float*)d_in[3];
  const float* W_proj  = (const float*)d_in[4];
  const float* b_proj  = (const float*)d_in[5];

  float* out   = (float*)d_out;
  float* out_k = out   + (size_t)Bb*Tt*Cc;
  float* out_v = out_k + (size_t)Bb*Hh*CTX*Dd;

  if(ws_size < (size_t)67108864) return;  // need 64 MiB scratch
  char* ws = (char*)d_ws;
  // liveness-packed layout (timeline: pre, gemm, mid, attn, combine, gemm)
  unsigned short* WqkvT  = (unsigned short*)(ws);              // [0,25952256) 6144x2112
  unsigned short* Vt_ws  = (unsigned short*)(ws);              // [0,17039360) after gemm
  unsigned short* attn_ws= (unsigned short*)(ws);              // [0,8650752) after attn
  unsigned short* WprojT = (unsigned short*)(ws + 17039360);   // [17039360,25690112)
  unsigned short* Kws    = (unsigned short*)(ws + 25952256);   // [25952256,42729472)
  unsigned short* q_ws   = (unsigned short*)(ws + 42729472);   // [42729472,51118080)
  unsigned short* x_bf   = (unsigned short*)(ws + 51118080);   // [51118080,59768832)
  unsigned short* O1b    = (unsigned short*)(ws + 51118080);   // after gemm (attn out)
  float*          ml     = (float*)(ws + 59768832);            // [59768832,60293120)
  float*          O0     = out;                                // out slot as scratch

  fused_pre_k<<<dim3(20480), 256, 0, stream>>>(
      W_qkv, WqkvT, (const float4*)x, x_bf,
      (const float4*)cache_k, (const float4*)cache_v,
      (float4*)out_k, (float4*)out_v, Kws);
  gemm_t<0,48><<<dim3(768), 256, 0, stream>>>(x_bf, WqkvT, q_ws, out_k, out_v, Kws,
                                              nullptr, nullptr);
  fused_mid_k<<<dim3(12288), 256, 0, stream>>>(out_v, Vt_ws, W_proj, WprojT);
  attn_k<<<dim3(8,2,32), 256, 0, stream>>>(q_ws, Kws, Vt_ws, O0, O1b, ml);
  combine_k<<<dim3(16384), 256, 0, stream>>>(O0, O1b, ml, attn_ws);
  gemm_t<1,16><<<dim3(256), 256, 0, stream>>>(attn_ws, WprojT, nullptr, nullptr, nullptr,
                                              nullptr, b_proj, out);
}

// Round 10
// 202.004 us; speedup vs baseline: 1.0369x; 1.0369x over previous
//
#include <hip/hip_runtime.h>
#include <hip/hip_bf16.h>

typedef __attribute__((ext_vector_type(8))) short bf16x8;
typedef __attribute__((ext_vector_type(4))) float f32x4;
typedef __attribute__((ext_vector_type(16))) float f32x16;

#define DI __device__ __forceinline__

static constexpr int Bb  = 2;
static constexpr int Tt  = 1024;
static constexpr int Cc  = 2048;
static constexpr int Hh  = 16;
static constexpr int Dd  = 128;
static constexpr int TC  = 1024;   // cached tokens (seq_start)
static constexpr int CTX = 2048;   // total context
static constexpr float QSCALE = 0.08838834764831845f; // 1/sqrt(128)

DI unsigned short f2bf(float f){
  unsigned u = __builtin_bit_cast(unsigned, f);
  u += 0x7FFFu + ((u >> 16) & 1u);
  return (unsigned short)(u >> 16);
}
DI float bf2f(unsigned short s){
  return __builtin_bit_cast(float, (unsigned)s << 16);
}
DI unsigned pk2(float a, float b){
  return (unsigned)f2bf(a) | ((unsigned)f2bf(b) << 16);
}
DI bf16x8 mk4(unsigned a, unsigned b, unsigned c, unsigned d){
  union{ unsigned u[4]; bf16x8 v; } x;
  x.u[0]=a; x.u[1]=b; x.u[2]=c; x.u[3]=d; return x.v;
}
DI f32x16 mfma32(bf16x8 a, bf16x8 b, f32x16 c){
  return __builtin_amdgcn_mfma_f32_32x32x16_bf16(a, b, c, 0, 0, 0);
}
#define MFMA16(a,b,c) __builtin_amdgcn_mfma_f32_16x16x32_bf16(a,b,c,0,0,0)
DI void gld16(const void* g, void* l){
  __builtin_amdgcn_global_load_lds(
      (const __attribute__((address_space(1))) unsigned int*)g,
      (__attribute__((address_space(3))) unsigned int*)l, 16, 0, 0);
}
DI unsigned ldsoff(const void* p){
  return (unsigned)(size_t)(const __attribute__((address_space(3))) void*)p;
}
// inline-asm LDS read: compiler-invisible (manual lgkmcnt + sched_barrier required)
template<int OFF>
DI bf16x8 dsr(unsigned addr){
  bf16x8 v;
  if constexpr (OFF == 0)
    asm volatile("ds_read_b128 %0, %1" : "=v"(v) : "v"(addr));
  else
    asm volatile("ds_read_b128 %0, %1 offset:%2" : "=v"(v) : "v"(addr), "i"(OFF));
  return v;
}
// NO-CLOBBER fences: invisible to the waitcnt pass -> no implicit vmcnt(0) drain
#define BARNC   asm volatile("s_barrier")
#define LGKM0   asm volatile("s_waitcnt lgkmcnt(0)")
#define VMCNT4  asm volatile("s_waitcnt vmcnt(4)")
#define VMCNT3  asm volatile("s_waitcnt vmcnt(3)")
#define VMCNT0  asm volatile("s_waitcnt vmcnt(0)")
#define SBAR    __builtin_amdgcn_sched_barrier(0)

// ---- shared transpose body: fp32 [R][C] -> bf16 [C][ostride] swizzled ----
DI void transpose_body(const float* in, unsigned short* out,
                       int C, int ostride, int r0, int c0, int mode,
                       unsigned short (*tile)[33]){
  int tx = threadIdx.x & 31, ty = threadIdx.x >> 5;
#pragma unroll
  for(int i=0;i<4;i++){
    int r = r0 + ty + i*8;
    tile[ty + i*8][tx] = f2bf(in[(size_t)r * C + c0 + tx]);
  }
  __syncthreads();
#pragma unroll
  for(int i=0;i<4;i++){
    int c = c0 + ty + i*8;     // out row
    int k = r0 + tx;           // out col (logical)
    int kp;
    if(mode == 0)
      kp = (k & ~24) | ((((k>>3)&3) ^ ((c>>1)&3)) << 3);
    else
      kp = (k & ~56) | ((((k>>3)&7) ^ (c&7)) << 3);
    out[(size_t)c * ostride + kp] = tile[tx][ty + i*8];
  }
}

// ---- fused pre-work: W_qkv^T (MODE 0, stride 2048) + x conv (MODE 0) ----
__global__ __launch_bounds__(256) void fused_pre_k(
    const float* __restrict__ W_qkv, unsigned short* __restrict__ WqkvT,
    const float4* __restrict__ x4, unsigned short* __restrict__ xbf){
  __shared__ unsigned short tile[32][33];
  int bid = blockIdx.x;
  if(bid < 12288){
    int bx = bid % 192, by = bid / 192;
    transpose_body(W_qkv, WqkvT, 6144, 2048, by*32, bx*32, 0, tile);
  } else {
    int idx = (bid - 12288) * 256 + threadIdx.x;   // x: 2048*2048/4
    int m = idx >> 9;
    int c4 = (idx & 511) * 4;
    float4 v = x4[idx];
    int cp = (c4 & ~24) | ((((c4>>3)&3) ^ ((m>>1)&3)) << 3);
    uint2 p; p.x = pk2(v.x, v.y); p.y = pk2(v.z, v.w);
    *(uint2*)(xbf + (size_t)m * Cc + cp) = p;
  }
}

// ===== fused QKV GEMM (768 blocks) + shadow copy work (12288 blocks) =====
// gemm: 128x128, BK=32, counted vmcnt, MODE-0 swizzled operands, stride 2048.
// shadow: cache_copy(+Kws), W_proj^T, cached-V^T -> Vt (runs in gemm's idle BW).
__global__ __launch_bounds__(256, 4) void gemmA_k(
    const unsigned short* __restrict__ A, const unsigned short* __restrict__ BT,
    unsigned short* __restrict__ q_ws, float* __restrict__ out_k,
    float* __restrict__ out_v, unsigned short* __restrict__ Kws,
    unsigned short* __restrict__ Vt,
    const float4* __restrict__ ck, const float4* __restrict__ cv,
    const float* __restrict__ W_proj, unsigned short* __restrict__ WprojT){
  __shared__ unsigned short Al[2][128*32];   // 16 KiB
  __shared__ unsigned short Bl[2][128*32];   // 16 KiB
  int bid = blockIdx.x;
  int tid = threadIdx.x;

  if(bid >= 768){
    if(bid < 4864){
      // cache copy: k/v fp32 + swizzled bf16 K
      int idx = (bid - 768) * 256 + tid;
      const int per = TC * Dd / 4;                 // 32768 per (b,h)
      int bh = idx / per, r = idx - bh * per;
      int dst = bh * (CTX * Dd / 4) + r;
      float4 kv = ck[idx];
      ((float4*)out_k)[dst] = kv;
      ((float4*)out_v)[dst] = cv[idx];
      int key = r >> 5, dq = (r & 31) * 4;
      int dp = (((dq>>3) ^ (key&7)) << 3) | (dq & 7);
      uint2 p; p.x = pk2(kv.x, kv.y); p.y = pk2(kv.z, kv.w);
      *(uint2*)(Kws + ((size_t)bh * CTX + key) * Dd + dp) = p;
    } else if(bid < 8960){
      // W_proj^T (MODE 0, stride 2048)
      int b2 = bid - 4864;
      int bx = b2 & 63, by = b2 >> 6;
      transpose_body(W_proj, WprojT, 2048, 2048, by*32, bx*32, 0,
                     (unsigned short(*)[33])&Al[0][0]);
    } else {
      // cached V^T: cv [bh][1024 keys][128 d] -> Vt [bh][d][keys 0..1023] (MODE 1)
      int zz = bid - 8960;
      int bh = zz >> 7, rem = zz & 127;
      int bx = rem & 3, by = rem >> 2;
      transpose_body((const float*)cv + (size_t)bh*131072,
                     Vt + (size_t)bh*262144, 128, CTX, by*32, bx*32, 1,
                     (unsigned short(*)[33])&Al[0][0]);
    }
    return;
  }

  // ---- gemm branch ----
  int lane = tid & 63, w = tid >> 6;
  int lr = lane & 15, lg = lane >> 4;
  constexpr int NWG = 768;
  int swz = (bid & 7) * (NWG/8) + (bid >> 3);
  int m0 = (swz & 15) * 128;
  int n0 = (swz >> 4) * 128;
  int wr = (w >> 1) * 64, wc = (w & 1) * 64;
  int fsw = (lg ^ ((lr >> 1) & 3)) << 3;

  unsigned baseAb = ldsoff(Al) + (unsigned)(((wr + lr)*32 + fsw)*2);
  unsigned baseBb = ldsoff(Bl) + (unsigned)(((wc + lr)*32 + fsw)*2);

  f32x4 acc[4][4];
#pragma unroll
  for(int i=0;i<4;i++)
#pragma unroll
    for(int j=0;j<4;j++) acc[i][j] = (f32x4){0.f,0.f,0.f,0.f};

  auto stage = [&](int buf, int k0){
#pragma unroll
    for(int li=0; li<2; li++){
      int rb = w*32 + li*16;
      gld16(A  + (size_t)(m0 + rb + (lane>>2))*Cc + k0 + (lane&3)*8, &Al[buf][rb*32]);
      gld16(BT + (size_t)(n0 + rb + (lane>>2))*Cc + k0 + (lane&3)*8, &Bl[buf][rb*32]);
    }
  };
  stage(0, 0);                      // 4 loads in flight
  int buf = 0;
#pragma unroll 1
  for(int k0 = 0; k0 < Cc; k0 += 32){
    SBAR;
    if(k0 + 32 < Cc){
      stage(buf^1, k0 + 32);        // +4 -> 8 in flight
      SBAR;
      VMCNT4;                       // buf's 4 landed; next-buf 4 stay in flight
    } else {
      SBAR;
      VMCNT0;
    }
    BARNC;
    unsigned aA = baseAb + (unsigned)buf*8192u;
    unsigned aB = baseBb + (unsigned)buf*8192u;
    bf16x8 af[4], bfr[4];
    af[0]  = dsr<0>(aA);    af[1]  = dsr<1024>(aA);
    af[2]  = dsr<2048>(aA); af[3]  = dsr<3072>(aA);
    bfr[0] = dsr<0>(aB);    bfr[1] = dsr<1024>(aB);
    bfr[2] = dsr<2048>(aB); bfr[3] = dsr<3072>(aB);
    LGKM0;
    SBAR;
    __builtin_amdgcn_s_setprio(1);
#pragma unroll
    for(int mi=0;mi<4;mi++)
#pragma unroll
      for(int ni=0;ni<4;ni++)
        acc[mi][ni] = MFMA16(af[mi], bfr[ni], acc[mi][ni]);
    __builtin_amdgcn_s_setprio(0);
    SBAR;
    BARNC;
    buf ^= 1;
  }

  // epilogue: QKV scatter (+Kws bf16, +Vt bf16 transposed)
#pragma unroll
  for(int mi=0;mi<4;mi++){
#pragma unroll
    for(int ni=0;ni<4;ni++){
      int n = n0 + wc + ni*16 + lr;
      int seg = n >> 11;
      int h = (n >> 7) & 15, d = n & 127;
#pragma unroll
      for(int r=0;r<4;r++){
        int mrow = m0 + wr + mi*16 + lg*4 + r;
        float v = acc[mi][ni][r];
        int b = mrow >> 10, t = mrow & 1023;
        if(seg == 0){
          q_ws[((size_t)(b*Hh + h)*Tt + t)*Dd + d] = f2bf(v * QSCALE);
        } else if(seg == 1){
          int key = TC + t;
          size_t base = (size_t)(b*Hh + h)*CTX + key;
          out_k[base*Dd + d] = v;
          int dp = (((d>>3) ^ (key&7)) << 3) | (d & 7);
          Kws[base*Dd + dp] = f2bf(v);
        } else {
          int key = TC + t;
          out_v[((size_t)(b*Hh + h)*CTX + key)*Dd + d] = v;
          int kp = (key & ~56) | ((((key>>3)&7) ^ (d&7)) << 3);
          Vt[(size_t)(b*Hh + h)*(Dd*CTX) + (size_t)d*CTX + kp] = f2bf(v);
        }
      }
    }
  }
}

// ---- proj GEMM: 64x128 tiles, grid 512 (2 blocks/CU), vmcnt(3) ledger ----
__global__ __launch_bounds__(256, 4) void gemmp_k(
    const unsigned short* __restrict__ A, const unsigned short* __restrict__ BT,
    const float* __restrict__ bias, float* __restrict__ outp){
  __shared__ unsigned short Al[2][64*32];    // 8 KiB
  __shared__ unsigned short Bl[2][128*32];   // 16 KiB
  int tid = threadIdx.x, lane = tid & 63, w = tid >> 6;
  int lr = lane & 15, lg = lane >> 4;
  int bid = blockIdx.x;                      // 512 blocks
  int swz = (bid & 7) * 64 + (bid >> 3);
  int m0 = (swz & 31) * 64;
  int n0 = (swz >> 5) * 128;
  int wm2 = (w >> 1) * 32, wn2 = (w & 1) * 64;
  int fsw = (lg ^ ((lr >> 1) & 3)) << 3;

  unsigned baseAb = ldsoff(Al) + (unsigned)(((wm2 + lr)*32 + fsw)*2);
  unsigned baseBb = ldsoff(Bl) + (unsigned)(((wn2 + lr)*32 + fsw)*2);

  f32x4 acc[2][4];
#pragma unroll
  for(int i=0;i<2;i++)
#pragma unroll
    for(int j=0;j<4;j++) acc[i][j] = (f32x4){0.f,0.f,0.f,0.f};

  auto stage = [&](int buf, int k0){
    gld16(A + (size_t)(m0 + w*16 + (lane>>2))*Cc + k0 + (lane&3)*8,
          &Al[buf][w*16*32]);
#pragma unroll
    for(int li=0; li<2; li++){
      int rb = w*32 + li*16;
      gld16(BT + (size_t)(n0 + rb + (lane>>2))*Cc + k0 + (lane&3)*8, &Bl[buf][rb*32]);
    }
  };
  stage(0, 0);                      // 3 loads in flight
  int buf = 0;
#pragma unroll 1
  for(int k0 = 0; k0 < Cc; k0 += 32){
    SBAR;
    if(k0 + 32 < Cc){
      stage(buf^1, k0 + 32);        // +3 -> 6 in flight
      SBAR;
      VMCNT3;                       // buf's 3 landed
    } else {
      SBAR;
      VMCNT0;
    }
    BARNC;
    unsigned aA = baseAb + (unsigned)buf*4096u;
    unsigned aB = baseBb + (unsigned)buf*8192u;
    bf16x8 af[2], bfr[4];
    af[0]  = dsr<0>(aA);    af[1]  = dsr<1024>(aA);
    bfr[0] = dsr<0>(aB);    bfr[1] = dsr<1024>(aB);
    bfr[2] = dsr<2048>(aB); bfr[3] = dsr<3072>(aB);
    LGKM0;
    SBAR;
    __builtin_amdgcn_s_setprio(1);
#pragma unroll
    for(int mi=0;mi<2;mi++)
#pragma unroll
      for(int ni=0;ni<4;ni++)
        acc[mi][ni] = MFMA16(af[mi], bfr[ni], acc[mi][ni]);
    __builtin_amdgcn_s_setprio(0);
    SBAR;
    BARNC;
    buf ^= 1;
  }

#pragma unroll
  for(int mi=0;mi<2;mi++){
#pragma unroll
    for(int ni=0;ni<4;ni++){
      int n = n0 + wn2 + ni*16 + lr;
#pragma unroll
      for(int r=0;r<4;r++){
        int mrow = m0 + wm2 + mi*16 + lg*4 + r;
        outp[(size_t)mrow * Cc + n] = acc[mi][ni][r] + bias[n];
      }
    }
  }
}

// ---- flash attention, swapped-QK 32x32, 4 waves x 32q, key-split x2 ----
__global__ __launch_bounds__(256, 2) void attn_k(
    const unsigned short* __restrict__ q_ws,
    const unsigned short* __restrict__ Kws,
    const unsigned short* __restrict__ Vt,
    float* __restrict__ O0, unsigned short* __restrict__ O1b,
    float* __restrict__ ml){
  __shared__ unsigned short Kl[2][64*128];   // [key][128] swizzled
  __shared__ unsigned short Vl[2][128*64];   // [d][64]  swizzled
  int tid = threadIdx.x, lane = tid & 63, w = tid >> 6;
  int l31 = lane & 31, hi = lane >> 5, r7 = l31 & 7;
  int qt = blockIdx.x, split = blockIdx.y, bh = blockIdx.z;
  int q0b = qt * 128, qw0 = q0b + w * 32;
  const unsigned short* Kb = Kws + (size_t)bh * CTX * Dd;
  const unsigned short* Vb = Vt  + (size_t)bh * Dd * CTX;

  const unsigned short* qp = q_ws + ((size_t)bh * Tt + qw0 + l31) * Dd + hi * 8;
  bf16x8 qf[8];
#pragma unroll
  for(int ks=0;ks<8;ks++) qf[ks] = *(const bf16x8*)(qp + ks*16);

  f32x16 o[4];
#pragma unroll
  for(int dt=0;dt<4;dt++)
#pragma unroll
    for(int r=0;r<16;r++) o[dt][r] = 0.f;
  float m = -3e38f, l = 0.f;

  int nts = ((TC + q0b + 128) >> 6) >> 1;   // tiles for this split

  auto stageK = [&](int buf, int j0){
#pragma unroll
    for(int li=0; li<4; li++){
      gld16(Kb + (size_t)(j0 + w*16 + li*4 + (lane>>4))*Dd + (lane&15)*8,
            &Kl[buf][(w*16 + li*4)*128]);
    }
  };
  auto stageV = [&](int buf, int j0){
#pragma unroll
    for(int li=0; li<4; li++){
      gld16(Vb + (size_t)(w*32 + li*8 + (lane>>3))*CTX + j0 + (lane&7)*8,
            &Vl[buf][(w*32 + li*8)*64]);
    }
  };

  stageK(0, split*64); stageV(0, split*64);
  __syncthreads();
  int buf = 0;
#pragma unroll 1
  for(int t = 0; t < nts; t++){
    int j0 = (2*t + split) * 64;
    if(t + 1 < nts){ stageK(buf^1, j0 + 128); stageV(buf^1, j0 + 128); }

    if(j0 <= TC + qw0 + 31){
      f32x16 s0, s1;
#pragma unroll
      for(int r=0;r<16;r++){ s0[r] = 0.f; s1[r] = 0.f; }
#pragma unroll
      for(int ks=0; ks<8; ks++){
        int ub = ((ks*2 + hi) ^ r7) << 3;
        bf16x8 kf0 = *(const bf16x8*)&Kl[buf][l31*128 + ub];
        bf16x8 kf1 = *(const bf16x8*)&Kl[buf][(32+l31)*128 + ub];
        s0 = mfma32(kf0, qf[ks], s0);
        s1 = mfma32(kf1, qf[ks], s1);
      }
      int qabs = TC + qw0 + l31;
      if(j0 + 63 > TC + qw0){
#pragma unroll
        for(int r=0;r<16;r++){
          int kk = (r&3) + 8*(r>>2) + 4*hi;
          if(j0 + kk > qabs)      s0[r] = -1e30f;
          if(j0 + 32 + kk > qabs) s1[r] = -1e30f;
        }
      }
      float tm = fmaxf(s0[0], s1[0]);
#pragma unroll
      for(int r=1;r<16;r++) tm = fmaxf(tm, fmaxf(s0[r], s1[r]));
      tm = fmaxf(tm, __shfl_xor(tm, 32, 64));
      if(!__all(tm - m <= 8.f)){
        float mn = fmaxf(m, tm);
        float alpha = __expf(m - mn);
        m = mn;
        l *= alpha;
        float ar[16];
#pragma unroll
        for(int r=0;r<16;r++){
          int kk = (r&3) + 8*(r>>2) + 4*hi;
          ar[r] = __shfl(alpha, kk, 64);
        }
#pragma unroll
        for(int dt=0;dt<4;dt++)
#pragma unroll
          for(int r=0;r<16;r++) o[dt][r] *= ar[r];
      }
#pragma unroll
      for(int r=0;r<16;r++){ s0[r] = __expf(s0[r] - m); s1[r] = __expf(s1[r] - m); }
      float ts = 0.f;
#pragma unroll
      for(int r=0;r<16;r++) ts += s0[r] + s1[r];
      ts += __shfl_xor(ts, 32, 64);
      l += ts;
#pragma unroll
      for(int ks16=0; ks16<4; ks16++){
        f32x16 p = (ks16 & 2) ? s1 : s0;
        int fb = (ks16 & 1) * 8;
        unsigned e0 = pk2(p[fb+0], p[fb+1]);
        unsigned e1 = pk2(p[fb+2], p[fb+3]);
        unsigned e2 = pk2(p[fb+4], p[fb+5]);
        unsigned e3 = pk2(p[fb+6], p[fb+7]);
        unsigned x0 = __shfl_xor(e0, 32, 64);
        unsigned x1 = __shfl_xor(e1, 32, 64);
        unsigned x2 = __shfl_xor(e2, 32, 64);
        unsigned x3 = __shfl_xor(e3, 32, 64);
        bf16x8 pa = mk4(hi ? x2 : e0, hi ? x3 : e1, hi ? e2 : x0, hi ? e3 : x1);
        int ub = ((ks16*2 + hi) ^ r7) << 3;
#pragma unroll
        for(int dt=0; dt<4; dt++){
          bf16x8 vf = *(const bf16x8*)&Vl[buf][(dt*32 + l31)*64 + ub];
          o[dt] = mfma32(pa, vf, o[dt]);
        }
      }
    }
    __syncthreads();
    buf ^= 1;
  }

  if(split == 0){
#pragma unroll
    for(int dt=0; dt<4; dt++)
#pragma unroll
      for(int r=0; r<16; r++){
        int q = qw0 + (r&3) + 8*(r>>2) + 4*hi;
        O0[((size_t)bh*Tt + q)*Dd + dt*32 + l31] = o[dt][r];
      }
  } else {
#pragma unroll
    for(int dt=0; dt<4; dt++)
#pragma unroll
      for(int r=0; r<16; r++){
        int q = qw0 + (r&3) + 8*(r>>2) + 4*hi;
        O1b[((size_t)bh*Tt + q)*Dd + dt*32 + l31] = f2bf(o[dt][r]);
      }
  }
  if(lane < 32){
    float* mlp = ml + (((size_t)split*32 + bh)*Tt + qw0 + l31)*2;
    mlp[0] = m; mlp[1] = l;
  }
}

// ---- combine split partials -> bf16 attn_ws (MODE-0 swizzle, stride 2048) ----
__global__ __launch_bounds__(256) void combine_k(
    const float* __restrict__ O0, const unsigned short* __restrict__ O1b,
    const float* __restrict__ ml, unsigned short* __restrict__ attn_ws){
  int tid = threadIdx.x;
  int d = tid & 127, rl = tid >> 7;
  int row = blockIdx.x * 2 + rl;          // bh*1024 + t
  int bh = row >> 10, t = row & 1023;
  const float* p0 = ml + ((size_t)bh * Tt + t) * 2;
  const float* p1 = ml + (((size_t)32 + bh) * Tt + t) * 2;
  float m0 = p0[0], l0 = p0[1], m1 = p1[0], l1 = p1[1];
  float M = fmaxf(m0, m1);
  float e0 = __expf(m0 - M), e1 = __expf(m1 - M);
  float inv = 1.f / (l0*e0 + l1*e1);
  size_t off = (size_t)row * Dd + d;
  float v = (O0[off]*e0 + bf2f(O1b[off])*e1) * inv;
  int b = bh >> 4, h = bh & 15;
  int mrow = b * Tt + t;
  int c = h * Dd + d;
  int cp = (c & ~24) | ((((c>>3)&3) ^ ((mrow>>1)&3)) << 3);
  attn_ws[(size_t)mrow * Cc + cp] = f2bf(v);
}

extern "C" void kernel_launch(void* const* d_in, const int* in_sizes, int n_in,
                              void* d_out, int out_size, void* d_ws, size_t ws_size,
                              hipStream_t stream){
  const float* x       = (const float*)d_in[0];
  const float* cache_k = (const float*)d_in[1];
  const float* cache_v = (const float*)d_in[2];
  const float* W_qkv   = (const float*)d_in[3];
  const float* W_proj  = (const float*)d_in[4];
  const float* b_proj  = (const float*)d_in[5];

  float* out   = (float*)d_out;
  float* out_k = out   + (size_t)Bb*Tt*Cc;
  float* out_v = out_k + (size_t)Bb*Hh*CTX*Dd;
  // Vt lives in the dead `out` slot until the final GEMM overwrites it
  unsigned short* Vt = (unsigned short*)out;          // 16,777,216 B exactly

  if(ws_size < (size_t)67108864) return;  // need 64 MiB scratch
  char* ws = (char*)d_ws;
  // stage-exact liveness packing (total = 67,108,864 B):
  unsigned short* WqkvT  = (unsigned short*)(ws);              // [0,25165824) s1w s2r
  float*          O0     = (float*)(ws);                       // [0,16777216) s4w s5r
  float*          ml     = (float*)(ws + 16777216);            // s4w s5r
  unsigned short* WprojT = (unsigned short*)(ws + 25165824);   // s2w s6r
  unsigned short* Kws    = (unsigned short*)(ws + 33554432);   // s2w s4r
  unsigned short* attn_ws= (unsigned short*)(ws + 33554432);   // s5w s6r (Kws dead)
  unsigned short* q_ws   = (unsigned short*)(ws + 50331648);   // s2w s4r
  unsigned short* x_bf   = (unsigned short*)(ws + 58720256);   // s1w s2r
  unsigned short* O1b    = (unsigned short*)(ws + 58720256);   // s4w s5r (x_bf dead)

  fused_pre_k<<<dim3(16384), 256, 0, stream>>>(W_qkv, WqkvT, (const float4*)x, x_bf);
  gemmA_k<<<dim3(13056), 256, 0, stream>>>(x_bf, WqkvT, q_ws, out_k, out_v, Kws, Vt,
                                           (const float4*)cache_k, (const float4*)cache_v,
                                           W_proj, WprojT);
  attn_k<<<dim3(8,2,32), 256, 0, stream>>>(q_ws, Kws, Vt, O0, O1b, ml);
  combine_k<<<dim3(16384), 256, 0, stream>>>(O0, O1b, ml, attn_ws);
  gemmp_k<<<dim3(512), 256, 0, stream>>>(attn_ws, WprojT, b_proj, out);
}